// Round 1
// baseline (225.313 us; speedup 1.0000x reference)
//
#include <hip/hip_runtime.h>

#define EPSF 1e-8f

__device__ __forceinline__ float wave_reduce_sum(float v) {
#pragma unroll
    for (int m = 32; m >= 1; m >>= 1)
        v += __shfl_xor(v, m, 64);
    return v;
}

// sum of squared diffs over 8 elements held as two float4
__device__ __forceinline__ float sq8(const float4& xa, const float4& xb,
                                     const float4& pa, const float4& pb) {
    float t, a = 0.f;
    t = xa.x - pa.x; a = fmaf(t, t, a);
    t = xa.y - pa.y; a = fmaf(t, t, a);
    t = xa.z - pa.z; a = fmaf(t, t, a);
    t = xa.w - pa.w; a = fmaf(t, t, a);
    t = xb.x - pb.x; a = fmaf(t, t, a);
    t = xb.y - pb.y; a = fmaf(t, t, a);
    t = xb.z - pb.z; a = fmaf(t, t, a);
    t = xb.w - pb.w; a = fmaf(t, t, a);
    return a;
}

// One wave (64 lanes) per row; lane handles 8 consecutive floats (d=512).
// Waves [0, NR) -> query rows, [NR, 2*NR) -> key rows.
// Features written transposed: U[r*NR + row], V[r*NR + row], r in [0,9).
// U has coef[e] folded into features 1..8; V holds raw key weights.
__global__ __launch_bounds__(256) void feat_kernel(
    const float* __restrict__ q, const float* __restrict__ k,
    const float* __restrict__ center,
    const float* __restrict__ outer_radius_p,
    const float* __restrict__ hole_radius_p,
    const float* __restrict__ entry_points,
    const float* __restrict__ strengths_p,
    const float* __restrict__ orientations_p,
    float* __restrict__ U, float* __restrict__ V, int NR)
{
    const int gid  = blockIdx.x * blockDim.x + threadIdx.x;
    const int wave = gid >> 6;
    const int lane = gid & 63;
    const bool is_key = wave >= NR;
    const int row = is_key ? wave - NR : wave;

    const float* x = (is_key ? k : q) + (size_t)row * 512 + lane * 8;
    const float4 xa = ((const float4*)x)[0];
    const float4 xb = ((const float4*)x)[1];

    const float* c = center + lane * 8;
    const float4 ca = ((const float4*)c)[0];
    const float4 cb = ((const float4*)c)[1];

    float acc[9];
    acc[0] = sq8(xa, xb, ca, cb);  // sum (x - center)^2

#pragma unroll
    for (int e = 0; e < 8; e++) {
        const float* p = entry_points + e * 512 + lane * 8;
        const float4 pa = ((const float4*)p)[0];
        const float4 pb = ((const float4*)p)[1];
        acc[1 + e] = sq8(xa, xb, pa, pb);  // sum (x - p_e)^2  (>= 0, matches max(.,0))
    }

#pragma unroll
    for (int r = 0; r < 9; r++) acc[r] = wave_reduce_sum(acc[r]);

    if (lane == 0) {
        const float R  = outer_radius_p[0];
        const float hr = hole_radius_p[0] / (R + EPSF);
        const float dist = sqrtf(acc[0]);
        float w;
        if (hr < 0.05f) {                 // gaussian branch
            const float td = dist / (R + EPSF);
            w = expf(-0.5f * td * td);
        } else {                          // torus-shell branch
            const float td = fabsf(dist - R);
            w = expf(-0.5f * td * td);
        }
        float* O = is_key ? V : U;
        O[row] = w;  // feature 0
#pragma unroll
        for (int e = 0; e < 8; e++) {
            float we = expf(-0.5f * acc[1 + e]);
            if (!is_key) {
                const float st = 1.f / (1.f + expf(-strengths_p[e]));
                const float cf = (st > 0.3f) ? st * tanhf(orientations_p[e]) : 0.f;
                we *= cf;
            }
            O[(size_t)(1 + e) * NR + row] = we;
        }
    }
}

// out[b,i,j] = dot(U[b,i,0:9], V[b,j,0:9]); each thread writes 4 j's (float4).
__global__ __launch_bounds__(256) void outer_kernel(
    const float* __restrict__ U, const float* __restrict__ V,
    float* __restrict__ out, int s, int NR)
{
    const int b = blockIdx.z;
    const int i = blockIdx.y;
    const int j = (blockIdx.x * 256 + threadIdx.x) * 4;
    const int rowU = b * s + i;
    const int rowV = b * s + j;

    float u[9];
#pragma unroll
    for (int r = 0; r < 9; r++) u[r] = U[(size_t)r * NR + rowU];  // block-uniform

    float4 acc = make_float4(0.f, 0.f, 0.f, 0.f);
#pragma unroll
    for (int r = 0; r < 9; r++) {
        const float4 v = *(const float4*)(V + (size_t)r * NR + rowV);
        acc.x = fmaf(u[r], v.x, acc.x);
        acc.y = fmaf(u[r], v.y, acc.y);
        acc.z = fmaf(u[r], v.z, acc.z);
        acc.w = fmaf(u[r], v.w, acc.w);
    }
    *(float4*)(out + (size_t)rowU * s + j) = acc;
}

extern "C" void kernel_launch(void* const* d_in, const int* in_sizes, int n_in,
                              void* d_out, int out_size, void* d_ws, size_t ws_size,
                              hipStream_t stream) {
    const float* q        = (const float*)d_in[0];
    const float* k        = (const float*)d_in[1];
    const float* center   = (const float*)d_in[2];
    const float* outer_r  = (const float*)d_in[3];
    const float* hole_r   = (const float*)d_in[4];
    const float* entry_p  = (const float*)d_in[5];
    const float* strengths    = (const float*)d_in[6];
    const float* orientations = (const float*)d_in[7];

    const int d  = 512;
    const int NR = in_sizes[0] / d;                 // b*s = 16384
    const int s  = (int)((long long)out_size / NR); // 2048
    const int b  = NR / s;                          // 8

    float* U = (float*)d_ws;                        // [9][NR]
    float* V = U + (size_t)9 * NR;                  // [9][NR]

    // kernel 1: one wave per row, 2*NR rows total
    const int threads1 = 256;
    const int blocks1  = (2 * NR * 64) / threads1;
    feat_kernel<<<blocks1, threads1, 0, stream>>>(
        q, k, center, outer_r, hole_r, entry_p, strengths, orientations, U, V, NR);

    // kernel 2: (s/1024) x s x b blocks, 256 threads, 4 j's per thread
    dim3 g2(s / (256 * 4), s, b);
    outer_kernel<<<g2, 256, 0, stream>>>(U, V, (float*)d_out, s, NR);
}

// Round 2
// 210.617 us; speedup vs baseline: 1.0698x; 1.0698x over previous
//
#include <hip/hip_runtime.h>

#define EPSF 1e-8f

__device__ __forceinline__ float wave_reduce_sum(float v) {
#pragma unroll
    for (int m = 32; m >= 1; m >>= 1)
        v += __shfl_xor(v, m, 64);
    return v;
}

// sum of squared diffs over 8 elements held as two float4
__device__ __forceinline__ float sq8(const float4& xa, const float4& xb,
                                     const float4& pa, const float4& pb) {
    float t, a = 0.f;
    t = xa.x - pa.x; a = fmaf(t, t, a);
    t = xa.y - pa.y; a = fmaf(t, t, a);
    t = xa.z - pa.z; a = fmaf(t, t, a);
    t = xa.w - pa.w; a = fmaf(t, t, a);
    t = xb.x - pb.x; a = fmaf(t, t, a);
    t = xb.y - pb.y; a = fmaf(t, t, a);
    t = xb.z - pb.z; a = fmaf(t, t, a);
    t = xb.w - pb.w; a = fmaf(t, t, a);
    return a;
}

// One wave (64 lanes) per row; lane handles 8 consecutive floats (d=512).
// Waves [0, NR) -> query rows, [NR, 2*NR) -> key rows.
// Features written transposed: U[r*NR + row], V[r*NR + row], r in [0,9).
// U has coef[e] folded into features 1..8; V holds raw key weights.
__global__ __launch_bounds__(256) void feat_kernel(
    const float* __restrict__ q, const float* __restrict__ k,
    const float* __restrict__ center,
    const float* __restrict__ outer_radius_p,
    const float* __restrict__ hole_radius_p,
    const float* __restrict__ entry_points,
    const float* __restrict__ strengths_p,
    const float* __restrict__ orientations_p,
    float* __restrict__ U, float* __restrict__ V, int NR)
{
    const int gid  = blockIdx.x * blockDim.x + threadIdx.x;
    const int wave = gid >> 6;
    const int lane = gid & 63;
    const bool is_key = wave >= NR;
    const int row = is_key ? wave - NR : wave;

    const float* x = (is_key ? k : q) + (size_t)row * 512 + lane * 8;
    const float4 xa = ((const float4*)x)[0];
    const float4 xb = ((const float4*)x)[1];

    const float* c = center + lane * 8;
    const float4 ca = ((const float4*)c)[0];
    const float4 cb = ((const float4*)c)[1];

    float acc[9];
    acc[0] = sq8(xa, xb, ca, cb);  // sum (x - center)^2

#pragma unroll
    for (int e = 0; e < 8; e++) {
        const float* p = entry_points + e * 512 + lane * 8;
        const float4 pa = ((const float4*)p)[0];
        const float4 pb = ((const float4*)p)[1];
        acc[1 + e] = sq8(xa, xb, pa, pb);  // sum (x - p_e)^2  (>= 0, matches max(.,0))
    }

#pragma unroll
    for (int r = 0; r < 9; r++) acc[r] = wave_reduce_sum(acc[r]);

    if (lane == 0) {
        const float R  = outer_radius_p[0];
        const float hr = hole_radius_p[0] / (R + EPSF);
        const float dist = sqrtf(acc[0]);
        float w;
        if (hr < 0.05f) {                 // gaussian branch
            const float td = dist / (R + EPSF);
            w = expf(-0.5f * td * td);
        } else {                          // torus-shell branch
            const float td = fabsf(dist - R);
            w = expf(-0.5f * td * td);
        }
        float* O = is_key ? V : U;
        O[row] = w;  // feature 0
#pragma unroll
        for (int e = 0; e < 8; e++) {
            float we = expf(-0.5f * acc[1 + e]);
            if (!is_key) {
                const float st = 1.f / (1.f + expf(-strengths_p[e]));
                const float cf = (st > 0.3f) ? st * tanhf(orientations_p[e]) : 0.f;
                we *= cf;
            }
            O[(size_t)(1 + e) * NR + row] = we;
        }
    }
}

// out[b,i,j] = dot(U[b,i,0:9], V[b,j,0:9]).
// Block computes a 16i x 1024j tile: V float4s loaded once into registers and
// reused across 16 rows (kills the 9:1 read amplification of the naive form);
// U staged in LDS (broadcast reads).
#define TILE_I 16
__global__ __launch_bounds__(256) void outer_kernel(
    const float* __restrict__ U, const float* __restrict__ V,
    float* __restrict__ out, int s, int NR)
{
    const int b  = blockIdx.z;
    const int i0 = blockIdx.y * TILE_I;
    const int j  = (blockIdx.x * 256 + threadIdx.x) * 4;

    __shared__ float u_s[9][TILE_I];
    if (threadIdx.x < 9 * TILE_I) {
        const int r  = threadIdx.x / TILE_I;
        const int ii = threadIdx.x % TILE_I;
        u_s[r][ii] = U[(size_t)r * NR + b * s + i0 + ii];
    }

    float4 v[9];
    const int rowV = b * s + j;
#pragma unroll
    for (int r = 0; r < 9; r++)
        v[r] = *(const float4*)(V + (size_t)r * NR + rowV);

    __syncthreads();

    float* orow = out + ((size_t)(b * s + i0)) * s + j;
#pragma unroll
    for (int ii = 0; ii < TILE_I; ii++) {
        float4 acc = make_float4(0.f, 0.f, 0.f, 0.f);
#pragma unroll
        for (int r = 0; r < 9; r++) {
            const float ur = u_s[r][ii];
            acc.x = fmaf(ur, v[r].x, acc.x);
            acc.y = fmaf(ur, v[r].y, acc.y);
            acc.z = fmaf(ur, v[r].z, acc.z);
            acc.w = fmaf(ur, v[r].w, acc.w);
        }
        *(float4*)(orow + (size_t)ii * s) = acc;
    }
}

extern "C" void kernel_launch(void* const* d_in, const int* in_sizes, int n_in,
                              void* d_out, int out_size, void* d_ws, size_t ws_size,
                              hipStream_t stream) {
    const float* q        = (const float*)d_in[0];
    const float* k        = (const float*)d_in[1];
    const float* center   = (const float*)d_in[2];
    const float* outer_r  = (const float*)d_in[3];
    const float* hole_r   = (const float*)d_in[4];
    const float* entry_p  = (const float*)d_in[5];
    const float* strengths    = (const float*)d_in[6];
    const float* orientations = (const float*)d_in[7];

    const int d  = 512;
    const int NR = in_sizes[0] / d;                 // b*s = 16384
    const int s  = (int)((long long)out_size / NR); // 2048
    const int b  = NR / s;                          // 8

    float* U = (float*)d_ws;                        // [9][NR]
    float* V = U + (size_t)9 * NR;                  // [9][NR]

    // kernel 1: one wave per row, 2*NR rows total
    const int threads1 = 256;
    const int blocks1  = (2 * NR * 64) / threads1;
    feat_kernel<<<blocks1, threads1, 0, stream>>>(
        q, k, center, outer_r, hole_r, entry_p, strengths, orientations, U, V, NR);

    // kernel 2: 16i x 1024j tiles
    dim3 g2(s / (256 * 4), s / TILE_I, b);
    outer_kernel<<<g2, 256, 0, stream>>>(U, V, (float*)d_out, s, NR);
}